// Round 7
// baseline (577.070 us; speedup 1.0000x reference)
//
#include <hip/hip_runtime.h>

// ---------------- types / helpers ----------------
typedef __bf16 bf16x8 __attribute__((ext_vector_type(8)));
typedef float f32x4 __attribute__((ext_vector_type(4)));
typedef unsigned short u16x8 __attribute__((ext_vector_type(8)));

__device__ __forceinline__ unsigned short f2bf(float f) {
  union { float f; unsigned int u; } v; v.f = f;
  unsigned int r = v.u + 0x7fffu + ((v.u >> 16) & 1u);  // RNE
  return (unsigned short)(r >> 16);
}

__device__ __forceinline__ void async16(const unsigned short* g, unsigned short* l) {
  __builtin_amdgcn_global_load_lds(
      (const __attribute__((address_space(1))) unsigned int*)g,
      (__attribute__((address_space(3))) unsigned int*)l, 16, 0, 0);
}

// ---------------- fused converts: all weights + memory + bias concat, ONE launch ------
__global__ void cvt_all(const float* __restrict__ q_w, const float* __restrict__ k_w,
                        const float* __restrict__ v_w, const float* __restrict__ o_w,
                        const float* __restrict__ f1w, const float* __restrict__ f2w,
                        const float* __restrict__ mem,
                        const float* __restrict__ q_b, const float* __restrict__ k_b,
                        const float* __restrict__ v_b,
                        unsigned short* __restrict__ WQ, unsigned short* __restrict__ WK,
                        unsigned short* __restrict__ WV, unsigned short* __restrict__ WO,
                        unsigned short* __restrict__ WF1, unsigned short* __restrict__ WF2,
                        unsigned short* __restrict__ MEMB, float* __restrict__ QKVB) {
  const int bid = blockIdx.x;
  const float* src; unsigned short* dst; float scale = 1.f; int base;
  if (bid < 1024)       { src = q_w; dst = WQ;  scale = 0.125f; base = 0; }
  else if (bid < 2048)  { src = k_w; dst = WK;  base = 1024; }
  else if (bid < 3072)  { src = v_w; dst = WV;  base = 2048; }
  else if (bid < 4096)  { src = o_w; dst = WO;  base = 3072; }
  else if (bid < 8192)  { src = f1w; dst = WF1; base = 4096; }
  else if (bid < 12288) { src = f2w; dst = WF2; base = 8192; }
  else if (bid < 13312) { src = mem; dst = MEMB; base = 12288; }
  else {  // bias concat (12 blocks, 3072 elems), q-bias pre-scaled
    const int i = (bid - 13312) * 256 + threadIdx.x;
    QKVB[i] = (i < 1024) ? q_b[i] * 0.125f : (i < 2048 ? k_b[i - 1024] : v_b[i - 2048]);
    return;
  }
  const int i = (bid - base) * 256 + threadIdx.x;
  float4 v = ((const float4*)src)[i];
  ushort4 o;
  o.x = f2bf(v.x * scale); o.y = f2bf(v.y * scale);
  o.z = f2bf(v.z * scale); o.w = f2bf(v.w * scale);
  ((ushort4*)dst)[i] = o;
}

// ---------------- LayerNorm (per 1024-row) -> bf16 ----------------
template <int PREFILL>
__global__ __launch_bounds__(256) void ln_bf16(
    const float* __restrict__ src, unsigned short* __restrict__ dst,
    const float* __restrict__ g, const float* __restrict__ be,
    const float* __restrict__ fbias, float* __restrict__ dout) {
  const int row = blockIdx.x, tid = threadIdx.x;
  const float4 v = ((const float4*)(src + (size_t)row * 1024))[tid];
  if (PREFILL) {
    const float4 fb = ((const float4*)fbias)[tid];
    float4 r;
    r.x = v.x + fb.x; r.y = v.y + fb.y; r.z = v.z + fb.z; r.w = v.w + fb.w;
    ((float4*)(dout + (size_t)row * 1024))[tid] = r;
  }
  float s = v.x + v.y + v.z + v.w;
  float qq = v.x * v.x + v.y * v.y + v.z * v.z + v.w * v.w;
#pragma unroll
  for (int off = 32; off; off >>= 1) { s += __shfl_xor(s, off); qq += __shfl_xor(qq, off); }
  __shared__ float ps[4], pq[4];
  const int w = tid >> 6, lane = tid & 63;
  if (lane == 0) { ps[w] = s; pq[w] = qq; }
  __syncthreads();
  if (tid == 0) { ps[0] = ps[0] + ps[1] + ps[2] + ps[3]; pq[0] = pq[0] + pq[1] + pq[2] + pq[3]; }
  __syncthreads();
  const float mu = ps[0] * (1.f / 1024.f);
  const float var = pq[0] * (1.f / 1024.f) - mu * mu;
  const float rs = rsqrtf(var + 1e-5f);
  const float4 gv = ((const float4*)g)[tid];
  const float4 bv = ((const float4*)be)[tid];
  ushort4 o;
  o.x = f2bf((v.x - mu) * rs * gv.x + bv.x);
  o.y = f2bf((v.y - mu) * rs * gv.y + bv.y);
  o.z = f2bf((v.z - mu) * rs * gv.z + bv.z);
  o.w = f2bf((v.w - mu) * rs * gv.w + bv.w);
  ((ushort4*)(dst + (size_t)row * 1024))[tid] = o;
}

// ---------------- GEMM: C[M,N] = A[M,K] @ B[N,K]^T (+ bias), m97-style ----------------
// (256,4): cap 128 regs — no spill, insurance vs co-compile perturbation (rule #19).
#define KOFF 6291456ull
#define VOFF 13631488ull
template <int EPI>
__global__ __launch_bounds__(256, 4) void gemm_bt(
    const unsigned short* __restrict__ A, const unsigned short* __restrict__ Bw,
    const float* __restrict__ bias, const float* __restrict__ resid,
    void* __restrict__ Cout, int M, int N, int K, int lda, int ldb, int NBN, int WM) {
  __shared__ __align__(16) unsigned short lA[128 * 32];
  __shared__ __align__(16) unsigned short lB[128 * 32];
  const int tid = threadIdx.x;
  const int w = tid >> 6, lane = tid & 63;
  const int lr = lane & 15, lq = lane >> 4;
  const int l = blockIdx.x;
  const int xcd = l & 7, r = l >> 3;
  const int bm = xcd * WM + (r % WM);
  const int rest = r / WM;
  const int bn = rest % NBN;
  const size_t koff = (size_t)(rest / NBN) * K;  // split-K offset
  const unsigned short* Ab = A + (size_t)bm * 128 * lda + koff;
  const unsigned short* Bb = Bw + (size_t)bn * 128 * ldb + koff;
  const int wm = (w & 1) << 6, wn = (w >> 1) << 6;
  f32x4 acc[4][4] = {};
  const int kiters = K >> 5;
  const int c0 = tid, c1 = 256 + tid;
  const int r0 = c0 >> 2, o0 = (c0 & 3) << 3;
  const int r1 = c1 >> 2, o1 = (c1 & 3) << 3;
  for (int kt = 0; kt < kiters; ++kt) {
    const int kb = kt << 5;
    __syncthreads();
    async16(Ab + (size_t)r0 * lda + kb + o0, lA + c0 * 8);
    async16(Bb + (size_t)r0 * ldb + kb + o0, lB + c0 * 8);
    async16(Ab + (size_t)r1 * lda + kb + o1, lA + c1 * 8);
    async16(Bb + (size_t)r1 * ldb + kb + o1, lB + c1 * 8);
    __syncthreads();
    bf16x8 af[4], bfr[4];
#pragma unroll
    for (int i = 0; i < 4; ++i) af[i] = *(const bf16x8*)(lA + (wm + i * 16 + lr) * 32 + lq * 8);
#pragma unroll
    for (int i = 0; i < 4; ++i) bfr[i] = *(const bf16x8*)(lB + (wn + i * 16 + lr) * 32 + lq * 8);
#pragma unroll
    for (int i = 0; i < 4; ++i)
#pragma unroll
      for (int j = 0; j < 4; ++j)
        acc[i][j] = __builtin_amdgcn_mfma_f32_16x16x32_bf16(af[i], bfr[j], acc[i][j], 0, 0, 0);
  }
  const int which = (bn * 128) >> 10;  // EPI5: 0=Q,1=K,2=V (block-uniform; 1024%128==0)
#pragma unroll
  for (int i = 0; i < 4; ++i) {
#pragma unroll
    for (int j = 0; j < 4; ++j) {
      const int colg = bn * 128 + wn + j * 16 + lr;
      const float bi = (EPI == 6) ? 0.f : bias[colg];
      const int rowg0 = bm * 128 + wm + i * 16 + lq * 4;
#pragma unroll
      for (int r2 = 0; r2 < 4; ++r2) {
        const int rowg = rowg0 + r2;
        const float val = acc[i][j][r2] + bi;
        if (EPI == 5) {
          const int t = rowg >> 4, bb = rowg & 15;
          const int hh = (colg >> 6) & 15, dd = colg & 63;
          const size_t nn = (size_t)(bb * 16 + hh);
          unsigned short* q16 = (unsigned short*)Cout;
          if (which == 0) {
            if (rowg >= 1024) q16[(nn * 384 + (t - 64)) * 64 + dd] = f2bf(val);
          } else if (which == 1) {
            q16[KOFF + (nn * 448 + t) * 64 + dd] = f2bf(val);
          } else {
            q16[VOFF + (nn * 448 + t) * 64 + dd] = f2bf(val);
          }
        } else {
          const size_t idx = (size_t)rowg * N + colg;
          if (EPI == 2) ((float*)Cout)[idx] = val + resid[idx];
          else if (EPI == 3) ((unsigned short*)Cout)[idx] = f2bf(fmaxf(val, 0.f));
          else if (EPI == 6) atomicAdd(&((float*)Cout)[idx], acc[i][j][r2]);
        }
      }
    }
  }
}

// ---------------- gemm3r: 256x256 / BK=32 / depth-3 ring / high-intensity waves -------
// ROUND-6 POSTMORTEM: 2-phase engine sat at the documented 2-phase ceiling (~600 TF,
// m233); swizzle zeroed conflicts (6.29M->0) with NO timing change (= m252 regime
// gate). Redesign attacks the three structural gaps vs the 8-phase template:
//  (1) per-wave tile 128x64 (acc 8x4): 12 ds_read_b128 per 32 MFMA (0.375/MFMA) ->
//      LDS pipe (~48 reads/CU/phase ~600cyc) balances MFMA pipe (~620cyc).
//  (2) ONE vmcnt + ONE barrier per K-tile (not per phase). Ledger: 4 loads/KT/wave;
//      after head vmcnt(4) only prev KT's 4 outstanding -> KT t-2's stages (which
//      filled buf t%3) are drained; barrier extends this to all waves' stages.
//      Last KT waits vmcnt(0) so nothing is in flight at endpgm.
//  (3) depth-3 LDS ring: stage KT t+2 -> buf (t+2)%3 = COLD buffer (not being read,
//      not next) -> zero region-level write/read hazards; ~4-phase landing windows.
// Phase 0: read A-mh0(4)+B(4), MFMA acc[0..3][*]; phase 1: read A-mh1(4) (B reused
// in regs), MFMA acc[4..7][*]. lgkmcnt(0)+sched_barrier before each MFMA cluster
// (rule #18); setprio(1) around MFMA (T5).
// T2 swizzle pair reused VERBATIM from round 6 (refcheck'd, 0 conflicts): LDS dest
// linear; global source col-unit (c&3)^((c>>3)&3); read col offset lsw.
#define WAITV4()  asm volatile("s_waitcnt vmcnt(4)" ::: "memory")
#define WAITV0()  asm volatile("s_waitcnt vmcnt(0)" ::: "memory")
#define WAITL0()  asm volatile("s_waitcnt lgkmcnt(0)" ::: "memory")
#define BAR()     do { __builtin_amdgcn_s_barrier(); __builtin_amdgcn_sched_barrier(0); } while (0)
#define SCHED()   __builtin_amdgcn_sched_barrier(0)

// stage half `h` (0/1) of K-tile ktv into ring buffer bufv: 1 A-chunk + 1 B-chunk
// per thread (chunk = 16B; region = 256 rows x 32 u16 = 1024 chunks, 4 chunks/row).
#define STG3(ktv, bufv, h) do { \
    const int c_ = ((h) << 9) + tid; \
    const int rw_ = c_ >> 2; \
    const int cu_ = (((c_ & 3) ^ ((c_ >> 3) & 3)) << 3); \
    async16(Ab + (size_t)rw_ * lda + ((ktv) << 5) + cu_, \
            (unsigned short*)lA3 + (bufv) * 8192 + c_ * 8); \
    async16(Bb + (size_t)rw_ * ldb + ((ktv) << 5) + cu_, \
            (unsigned short*)lB3 + (bufv) * 8192 + c_ * 8); } while (0)
#define RD_A3(dst, bufv, mh) \
  _Pragma("unroll") \
  for (int i = 0; i < 4; ++i) \
    dst[i] = *(const bf16x8*)((unsigned short*)lA3 + (bufv) * 8192 + \
                              (wm * 128 + (mh) * 64 + i * 16 + lr) * 32 + lsw)
#define RD_B3(dst, bufv) \
  _Pragma("unroll") \
  for (int j = 0; j < 4; ++j) \
    dst[j] = *(const bf16x8*)((unsigned short*)lB3 + (bufv) * 8192 + \
                              (wn * 64 + j * 16 + lr) * 32 + lsw)
#define MFMA16B(base, av, bv) \
  _Pragma("unroll") \
  for (int i = 0; i < 4; ++i) \
  _Pragma("unroll") \
  for (int j = 0; j < 4; ++j) \
    acc[(base) + i][j] = \
        __builtin_amdgcn_mfma_f32_16x16x32_bf16(av[i], bv[j], acc[(base) + i][j], 0, 0, 0)

template <int EPI, int KITERS>
__global__ __launch_bounds__(512, 1) void gemm3r(
    const unsigned short* __restrict__ A, const unsigned short* __restrict__ Bw,
    const float* __restrict__ bias, void* __restrict__ Cout,
    int N, int lda, int ldb, int MT, int NBN) {  // grid = 8 * MT * NBN * splitk
  __shared__ __align__(16) unsigned short lA3[3 * 8192];  // 3 x [256 rows][32 u16] = 48 KiB
  __shared__ __align__(16) unsigned short lB3[3 * 8192];  // 48 KiB
  const int tid = threadIdx.x;
  const int w = tid >> 6, lane = tid & 63;
  const int wm = w >> 2, wn = w & 3;            // wave grid 2 (M) x 4 (N)
  const int lr = lane & 15, lq = lane >> 4;
  const int lsw = (lq ^ ((lr >> 1) & 3)) << 3;  // T2 read col offset (round-6 proven)
  const int bid = blockIdx.x;
  const int xcd = bid & 7, r = bid >> 3;
  const int bm = xcd * MT + (r % MT);           // per-XCD contiguous A stripe
  const int rest = r / MT;
  const int bn = rest % NBN;
  const size_t koff = (size_t)(rest / NBN) * (KITERS * 32);  // split-K offset
  const unsigned short* Ab = A + (size_t)bm * 256 * lda + koff;
  const unsigned short* Bb = Bw + (size_t)bn * 256 * ldb + koff;

  f32x4 acc[8][4] = {};
  bf16x8 a0[4], a1[4], b[4];

  // prologue: stage KT0 -> buf0, KT1 -> buf1 (4 loads each)
  STG3(0, 0, 0); STG3(0, 0, 1);
  STG3(1, 1, 0); STG3(1, 1, 1);
  WAITV4();   // KT0's 4 landed; KT1's 4 stay in flight
  BAR();

  int buf = 0, sbuf = 2;
  for (int kt = 0; kt < KITERS; ++kt) {
    const bool st = (kt + 2) < KITERS;
    if (kt > 0) {
      if (kt == KITERS - 1) { WAITV0(); } else { WAITV4(); }
      BAR();
    }
    // ---- phase 0: stage half0 of kt+2 (cold buf) ; read A-mh0 + B ; MFMA rows 0-63
    if (st) STG3(kt + 2, sbuf, 0);
    RD_A3(a0, buf, 0);
    RD_B3(b, buf);
    WAITL0(); SCHED();
    __builtin_amdgcn_s_setprio(1);
    MFMA16B(0, a0, b);
    __builtin_amdgcn_s_setprio(0);
    // ---- phase 1: stage half1 of kt+2 ; read A-mh1 (B reused) ; MFMA rows 64-127
    if (st) STG3(kt + 2, sbuf, 1);
    RD_A3(a1, buf, 1);
    WAITL0(); SCHED();
    __builtin_amdgcn_s_setprio(1);
    MFMA16B(4, a1, b);
    __builtin_amdgcn_s_setprio(0);
    buf = (buf == 2) ? 0 : buf + 1;
    sbuf = (sbuf == 2) ? 0 : sbuf + 1;
  }

  // epilogue (lane->(row,col) mapping proven in gemm_bt/gemm8 across rounds 0-6)
#pragma unroll
  for (int j = 0; j < 4; ++j) {
    const int colg = bn * 256 + wn * 64 + j * 16 + lr;
    const float bi = (EPI == 6) ? 0.f : bias[colg];
#pragma unroll
    for (int i = 0; i < 8; ++i) {
      const int rowg0 = bm * 256 + wm * 128 + i * 16 + lq * 4;
#pragma unroll
      for (int r2 = 0; r2 < 4; ++r2) {
        const size_t idx = (size_t)(rowg0 + r2) * N + colg;
        if (EPI == 3) {
          ((unsigned short*)Cout)[idx] = f2bf(fmaxf(acc[i][j][r2] + bi, 0.f));
        } else {  // EPI == 6
          atomicAdd(&((float*)Cout)[idx], acc[i][j][r2]);
        }
      }
    }
  }
}

// ---------------- V transpose: vb[n][t][d] -> vt[n][d][t] ----------------
__global__ __launch_bounds__(256) void vtrans(const unsigned short* __restrict__ vb,
                                              unsigned short* __restrict__ vt) {
  __shared__ __align__(16) unsigned short ls[64][80];
  const int kc = blockIdx.x, n = blockIdx.y;
  const int tid = threadIdx.x;
#pragma unroll
  for (int i = 0; i < 2; ++i) {
    const int c = i * 256 + tid;
    const int kk = c >> 3, dc = (c & 7) << 3;
    u16x8 val = *(const u16x8*)(vb + ((size_t)n * 448 + kc * 64 + kk) * 64 + dc);
    *(u16x8*)&ls[kk][dc] = val;
  }
  __syncthreads();
#pragma unroll
  for (int i = 0; i < 2; ++i) {
    const int c = i * 256 + tid;
    const int d = c >> 3, kx = (c & 7) << 3;
    u16x8 o;
#pragma unroll
    for (int j = 0; j < 8; ++j) o[j] = ls[kx + j][d];
    *(u16x8*)(vt + ((size_t)n * 64 + d) * 448 + kc * 64 + kx) = o;
  }
}

// ---------------- fused attention, S^T formulation, 4 waves/block ----------------
#define PST 468  // P row stride (u16): dword stride 234 == 10 mod 32 -> ~2-way (free)
__global__ __launch_bounds__(256) void attn_kernel(
    const unsigned short* __restrict__ qt_, const unsigned short* __restrict__ kt_,
    const unsigned short* __restrict__ vt_, unsigned short* __restrict__ attn) {
  __shared__ __align__(16) unsigned short P[16 * PST];  // 14976 B
  __shared__ float Rm[4][16], Rs[4][16], Rc[4][16], Rv[4][16], R2[4][16];
  __shared__ __align__(16) float OT[4][16][17];         // per-wave transpose buffers
  const int id = blockIdx.x;
  const int xcd = id & 7, j0 = id >> 3;
  const int n = xcd * 32 + (j0 & 31), qt = j0 >> 5;  // qt 0..23
  const int b = n >> 4, h = n & 15;
  const int tid = threadIdx.x, w = tid >> 6, lane = tid & 63;
  const int lr = lane & 15, lq = lane >> 4;

  const unsigned short* qp = qt_ + ((size_t)n * 384 + qt * 16 + lr) * 64 + lq * 8;
  const bf16x8 q0 = *(const bf16x8*)qp;
  const bf16x8 q1 = *(const bf16x8*)(qp + 32);

  // phase 1: S^T for 7 k-tiles. acc[t][r] = S[q=lr][k = (w*7+t)*16 + 4*lq + r]
  f32x4 acc[7];
#pragma unroll
  for (int t = 0; t < 7; ++t) {
    const unsigned short* kp = kt_ + ((size_t)n * 448 + (w * 7 + t) * 16 + lr) * 64 + lq * 8;
    const bf16x8 k0 = *(const bf16x8*)kp;
    const bf16x8 k1 = *(const bf16x8*)(kp + 32);
    f32x4 a = {0.f, 0.f, 0.f, 0.f};
    a = __builtin_amdgcn_mfma_f32_16x16x32_bf16(k0, q0, a, 0, 0, 0);
    a = __builtin_amdgcn_mfma_f32_16x16x32_bf16(k1, q1, a, 0, 0, 0);
    acc[t] = a;
  }

  // ---- pass 1: row max ----
  f32x4 m4 = acc[0];
#pragma unroll
  for (int t = 1; t < 7; ++t) {
    m4[0] = fmaxf(m4[0], acc[t][0]); m4[1] = fmaxf(m4[1], acc[t][1]);
    m4[2] = fmaxf(m4[2], acc[t][2]); m4[3] = fmaxf(m4[3], acc[t][3]);
  }
  float m = fmaxf(fmaxf(m4[0], m4[1]), fmaxf(m4[2], m4[3]));
  m = fmaxf(m, __shfl_xor(m, 16));
  m = fmaxf(m, __shfl_xor(m, 32));
  if (lq == 0) Rm[w][lr] = m;
  __syncthreads();
  m = fmaxf(fmaxf(Rm[0][lr], Rm[1][lr]), fmaxf(Rm[2][lr], Rm[3][lr]));

  // ---- exp in place; pass 2: sum + nonzero count ----
  f32x4 s4 = {0.f, 0.f, 0.f, 0.f}, c4 = {0.f, 0.f, 0.f, 0.f};
#pragma unroll
  for (int t = 0; t < 7; ++t) {
#pragma unroll
    for (int r = 0; r < 4; ++r) {
      const float e = __expf(acc[t][r] - m);
      acc[t][r] = e;
      s4[r] += e;
      if (e > 0.f) c4[r] += 1.f;
    }
  }
  float s = (s4[0] + s4[1]) + (s4[2] + s4[3]);
  float cnt = (c4[0] + c4[1]) + (c4[2] + c4[3]);
  s += __shfl_xor(s, 16); s += __shfl_xor(s, 32);
  cnt += __shfl_xor(cnt, 16); cnt += __shfl_xor(cnt, 32);
  if (lq == 0) { Rs[w][lr] = s; Rc[w][lr] = cnt; }
  __syncthreads();
  s = (Rs[0][lr] + Rs[1][lr]) + (Rs[2][lr] + Rs[3][lr]);
  cnt = (Rc[0][lr] + Rc[1][lr]) + (Rc[2][lr] + Rc[3][lr]);
  const float inv = 1.f / s;
  const float mean = 1.f / cnt;  // sum(p) == 1

  // ---- pass 3: variance of p over nonzeros ----
  f32x4 d4 = {0.f, 0.f, 0.f, 0.f};
#pragma unroll
  for (int t = 0; t < 7; ++t) {
#pragma unroll
    for (int r = 0; r < 4; ++r) {
      const float p = acc[t][r] * inv;
      const float dd = p - mean;
      if (acc[t][r] > 0.f) d4[r] += dd * dd;
    }
  }
  float dv = (d4[0] + d4[1]) + (d4[2] + d4[3]);
  dv += __shfl_xor(dv, 16); dv += __shfl_xor(dv, 32);
  if (lq == 0) Rv[w][lr] = dv;
  __syncthreads();
  dv = (Rv[0][lr] + Rv[1][lr]) + (Rv[2][lr] + Rv[3][lr]);
  const float thr = mean - 0.5f * sqrtf(dv / (cnt - 1.f));

  // ---- pass 4: survivor renormalizer (row max always survives: p_max >= mean >= thr) ----
  f32x4 t4 = {0.f, 0.f, 0.f, 0.f};
#pragma unroll
  for (int t = 0; t < 7; ++t) {
#pragma unroll
    for (int r = 0; r < 4; ++r) {
      if (!(acc[t][r] * inv < thr)) t4[r] += acc[t][r];
    }
  }
  float s2 = (t4[0] + t4[1]) + (t4[2] + t4[3]);
  s2 += __shfl_xor(s2, 16); s2 += __shfl_xor(s2, 32);
  if (lq == 0) R2[w][lr] = s2;
  __syncthreads();
  s2 = (R2[0][lr] + R2[1][lr]) + (R2[2][lr] + R2[3][lr]);
  const float inv2 = 1.f / s2;

  // ---- write P[q=lr][k] bf16 (wave w covers k in [w*112, w*112+112)) ----
#pragma unroll
  for (int t = 0; t < 7; ++t) {
#pragma unroll
    for (int rp = 0; rp < 4; rp += 2) {
      const float v0 = (acc[t][rp] * inv < thr) ? 0.f : acc[t][rp] * inv2;
      const float v1 = (acc[t][rp + 1] * inv < thr) ? 0.f : acc[t][rp + 1] * inv2;
      const unsigned int u = (unsigned int)f2bf(v0) | ((unsigned int)f2bf(v1) << 16);
      *(unsigned int*)&P[lr * PST + (w * 7 + t) * 16 + lq * 4 + rp] = u;
    }
  }
  __syncthreads();

  // phase 3: out^T[d][q] = V^T(64x448) . P(448x16). Wave w owns d-tile [w*16, w*16+16).
  f32x4 o = {0.f, 0.f, 0.f, 0.f};
#pragma unroll
  for (int c = 0; c < 14; ++c) {
    union { ushort4 hh[2]; bf16x8 v; } bf;
    bf.hh[0] = *(const ushort4*)&P[lr * PST + c * 32 + lq * 8];
    bf.hh[1] = *(const ushort4*)&P[lr * PST + c * 32 + lq * 8 + 4];
    const bf16x8 a = *(const bf16x8*)(vt_ + ((size_t)n * 64 + w * 16 + lr) * 448 + c * 32 + lq * 8);
    o = __builtin_amdgcn_mfma_f32_16x16x32_bf16(a, bf.v, o, 0, 0, 0);
  }

  // transpose 16x16 tile via wave-private LDS (no barrier: same-wave write->read)
#pragma unroll
  for (int r = 0; r < 4; ++r) OT[w][lq * 4 + r][lr] = o[r];
  const int qrow = lane >> 2, dg = lane & 3;
  ushort4 ov;
  ov.x = f2bf(OT[w][dg * 4 + 0][qrow]);
  ov.y = f2bf(OT[w][dg * 4 + 1][qrow]);
  ov.z = f2bf(OT[w][dg * 4 + 2][qrow]);
  ov.w = f2bf(OT[w][dg * 4 + 3][qrow]);
  *(ushort4*)(attn + ((size_t)(qt * 16 + qrow) * 16 + b) * 1024 + h * 64 + w * 16 + dg * 4) = ov;
}

// ---------------- launch ----------------
extern "C" void kernel_launch(void* const* d_in, const int* in_sizes, int n_in,
                              void* d_out, int out_size, void* d_ws, size_t ws_size,
                              hipStream_t stream) {
  (void)in_sizes; (void)n_in; (void)out_size; (void)ws_size;
  const float* x    = (const float*)d_in[0];
  const float* mem  = (const float*)d_in[1];
  const float* q_w  = (const float*)d_in[2];
  const float* q_b  = (const float*)d_in[3];
  const float* k_w  = (const float*)d_in[4];
  const float* k_b  = (const float*)d_in[5];
  const float* v_w  = (const float*)d_in[6];
  const float* v_b  = (const float*)d_in[7];
  const float* o_w  = (const float*)d_in[8];
  const float* o_b  = (const float*)d_in[9];
  const float* ln1w = (const float*)d_in[10];
  const float* ln1b = (const float*)d_in[11];
  const float* f1w  = (const float*)d_in[12];
  const float* f1b  = (const float*)d_in[13];
  const float* f2w  = (const float*)d_in[14];
  const float* f2b  = (const float*)d_in[15];
  const float* ln2w = (const float*)d_in[16];
  const float* ln2b = (const float*)d_in[17];

  unsigned short* WQ   = (unsigned short*)d_ws;        // 3x 1048576 contiguous = fused B
  unsigned short* WK   = WQ + 1048576;
  unsigned short* WV   = WK + 1048576;
  unsigned short* WO   = WV + 1048576;
  unsigned short* WF1  = WO + 1048576;                 // 4194304
  unsigned short* WF2  = WF1 + 4194304;                // 4194304
  unsigned short* ABUF = WF2 + 4194304;                // 7340032 (mem rows 0..1023, xn rows 1024..7167)
  unsigned short* QB   = ABUF + 7340032;               // 6291456 [n][384][64]; KB/VB at KOFF/VOFF
  unsigned short* KB   = QB + 6291456;                 // 7340032 [n][448][64]
  unsigned short* VB   = KB + 7340032;                 // 7340032 [n][448][64]
  unsigned short* VT   = VB + 7340032;                 // 7340032 [n][64][448]
  unsigned short* ATTN = VT + 7340032;                 // 6291456
  float*          X2   = (float*)(ATTN + 6291456);     // 6291456 f32
  float*          QKVB = (float*)ATTN;                 // 3072 f32, dead before attn writes ATTN
  unsigned short* XN2  = ATTN;                         // alias (attn dead after out-proj)
  unsigned short* HB   = ABUF;                         // alias (A/q/k/v staging dead after attention)

  // all weight/memory converts + bias concat in ONE launch
  cvt_all<<<13324, 256, 0, stream>>>(q_w, k_w, v_w, o_w, f1w, f2w, mem, q_b, k_b, v_b,
                                     WQ, WK, WV, WO, WF1, WF2, ABUF, QKVB);

  // LN1 -> xn (rows 1024.. of ABUF)
  ln_bf16<0><<<6144, 256, 0, stream>>>(x, ABUF + 1048576, ln1w, ln1b, nullptr, nullptr);

  // fused QKV: [mem;xn] x [Wq;Wk;Wv]^T, head-major epilogue. NBM=56 -> WM=7, NBN=24.
  gemm_bt<5><<<1344, 256, 0, stream>>>(ABUF, WQ, QKVB, nullptr, QB, 7168, 3072, 1024, 1024, 1024, 24, 7);

  vtrans<<<dim3(7, 256), 256, 0, stream>>>(VB, VT);
  attn_kernel<<<6144, 256, 0, stream>>>(QB, KB, VT, ATTN);

  // out-proj + residual -> X2 (f32). NBM=48 -> WM=6, NBN=8.
  gemm_bt<2><<<384, 256, 0, stream>>>(ATTN, WO, o_b, x, X2, 6144, 1024, 1024, 1024, 1024, 8, 6);

  // LN2 -> xn2, and prefill d_out = X2 + fc2_bias (fc2 accumulates into it)
  ln_bf16<1><<<6144, 256, 0, stream>>>(X2, XN2, ln2w, ln2b, f2b, (float*)d_out);

  // FFN on the depth-3-ring engine.
  // fc1: 256x256 tiles, grid 384 = 8 XCD x (3 m x 16 n), KITERS=32 (K=1024).
  gemm3r<3, 32><<<384, 512, 0, stream>>>(XN2, WF1, f1b, HB, 4096, 1024, 1024, 3, 16);
  // fc2: K=4096 = KITERS(32)*32 * splitK(4). grid 384 = 8 XCD x (3 m x 4 n x 4 kz);
  //      atomicAdd f32 into prefilled d_out; kz-writers of a tile share an XCD/L2.
  gemm3r<6, 32><<<384, 512, 0, stream>>>(HB, WF2, nullptr, d_out, 1024, 4096, 4096, 3, 4);
}

// Round 8
// 528.737 us; speedup vs baseline: 1.0914x; 1.0914x over previous
//
#include <hip/hip_runtime.h>

// ---------------- types / helpers ----------------
typedef __bf16 bf16x8 __attribute__((ext_vector_type(8)));
typedef float f32x4 __attribute__((ext_vector_type(4)));
typedef unsigned short u16x8 __attribute__((ext_vector_type(8)));

__device__ __forceinline__ unsigned short f2bf(float f) {
  union { float f; unsigned int u; } v; v.f = f;
  unsigned int r = v.u + 0x7fffu + ((v.u >> 16) & 1u);  // RNE
  return (unsigned short)(r >> 16);
}

__device__ __forceinline__ void async16(const unsigned short* g, unsigned short* l) {
  __builtin_amdgcn_global_load_lds(
      (const __attribute__((address_space(1))) unsigned int*)g,
      (__attribute__((address_space(3))) unsigned int*)l, 16, 0, 0);
}

// ---------------- fused converts: all weights + memory + bias concat, ONE launch ------
__global__ void cvt_all(const float* __restrict__ q_w, const float* __restrict__ k_w,
                        const float* __restrict__ v_w, const float* __restrict__ o_w,
                        const float* __restrict__ f1w, const float* __restrict__ f2w,
                        const float* __restrict__ mem,
                        const float* __restrict__ q_b, const float* __restrict__ k_b,
                        const float* __restrict__ v_b,
                        unsigned short* __restrict__ WQ, unsigned short* __restrict__ WK,
                        unsigned short* __restrict__ WV, unsigned short* __restrict__ WO,
                        unsigned short* __restrict__ WF1, unsigned short* __restrict__ WF2,
                        unsigned short* __restrict__ MEMB, float* __restrict__ QKVB) {
  const int bid = blockIdx.x;
  const float* src; unsigned short* dst; float scale = 1.f; int base;
  if (bid < 1024)       { src = q_w; dst = WQ;  scale = 0.125f; base = 0; }
  else if (bid < 2048)  { src = k_w; dst = WK;  base = 1024; }
  else if (bid < 3072)  { src = v_w; dst = WV;  base = 2048; }
  else if (bid < 4096)  { src = o_w; dst = WO;  base = 3072; }
  else if (bid < 8192)  { src = f1w; dst = WF1; base = 4096; }
  else if (bid < 12288) { src = f2w; dst = WF2; base = 8192; }
  else if (bid < 13312) { src = mem; dst = MEMB; base = 12288; }
  else {  // bias concat (12 blocks, 3072 elems), q-bias pre-scaled
    const int i = (bid - 13312) * 256 + threadIdx.x;
    QKVB[i] = (i < 1024) ? q_b[i] * 0.125f : (i < 2048 ? k_b[i - 1024] : v_b[i - 2048]);
    return;
  }
  const int i = (bid - base) * 256 + threadIdx.x;
  float4 v = ((const float4*)src)[i];
  ushort4 o;
  o.x = f2bf(v.x * scale); o.y = f2bf(v.y * scale);
  o.z = f2bf(v.z * scale); o.w = f2bf(v.w * scale);
  ((ushort4*)dst)[i] = o;
}

// ---------------- LayerNorm (per 1024-row) -> bf16 ----------------
template <int PREFILL>
__global__ __launch_bounds__(256) void ln_bf16(
    const float* __restrict__ src, unsigned short* __restrict__ dst,
    const float* __restrict__ g, const float* __restrict__ be,
    const float* __restrict__ fbias, float* __restrict__ dout) {
  const int row = blockIdx.x, tid = threadIdx.x;
  const float4 v = ((const float4*)(src + (size_t)row * 1024))[tid];
  if (PREFILL) {
    const float4 fb = ((const float4*)fbias)[tid];
    float4 r;
    r.x = v.x + fb.x; r.y = v.y + fb.y; r.z = v.z + fb.z; r.w = v.w + fb.w;
    ((float4*)(dout + (size_t)row * 1024))[tid] = r;
  }
  float s = v.x + v.y + v.z + v.w;
  float qq = v.x * v.x + v.y * v.y + v.z * v.z + v.w * v.w;
#pragma unroll
  for (int off = 32; off; off >>= 1) { s += __shfl_xor(s, off); qq += __shfl_xor(qq, off); }
  __shared__ float ps[4], pq[4];
  const int w = tid >> 6, lane = tid & 63;
  if (lane == 0) { ps[w] = s; pq[w] = qq; }
  __syncthreads();
  if (tid == 0) { ps[0] = ps[0] + ps[1] + ps[2] + ps[3]; pq[0] = pq[0] + pq[1] + pq[2] + pq[3]; }
  __syncthreads();
  const float mu = ps[0] * (1.f / 1024.f);
  const float var = pq[0] * (1.f / 1024.f) - mu * mu;
  const float rs = rsqrtf(var + 1e-5f);
  const float4 gv = ((const float4*)g)[tid];
  const float4 bv = ((const float4*)be)[tid];
  ushort4 o;
  o.x = f2bf((v.x - mu) * rs * gv.x + bv.x);
  o.y = f2bf((v.y - mu) * rs * gv.y + bv.y);
  o.z = f2bf((v.z - mu) * rs * gv.z + bv.z);
  o.w = f2bf((v.w - mu) * rs * gv.w + bv.w);
  ((ushort4*)(dst + (size_t)row * 1024))[tid] = o;
}

// ---------------- GEMM: C[M,N] = A[M,K] @ B[N,K]^T (+ bias), m97-style ----------------
// ROUND-7 POSTMORTEM: three deep-pipeline engines (2-phase BK=64, +swizzle, depth-3
// ring BK=32; rounds 1-7) all landed at parity-or-worse vs this kernel, with the
// same signature: MfmaUtil ~14%, VALUBusy ~6%, Occupancy ~15% — ALL pipes idle =
// latency-bound at 1 block/CU (512 thr + 96KB LDS leaves the CU nothing to switch
// to at barriers). This 256-thr/16KB/56-VGPR kernel keeps 3-6 blocks/CU co-resident
// and lets m114-style implicit wave overlap do the pipelining. Engine family closed;
// the lever here is TLP via grid size.
// (256,4): cap 128 regs — no spill ((256,8) forced VGPR=32 -> scratch catastrophe,
// round 2), insurance vs co-compile perturbation (rule #19).
#define KOFF 6291456ull
#define VOFF 13631488ull
template <int EPI>
__global__ __launch_bounds__(256, 4) void gemm_bt(
    const unsigned short* __restrict__ A, const unsigned short* __restrict__ Bw,
    const float* __restrict__ bias, const float* __restrict__ resid,
    void* __restrict__ Cout, int M, int N, int K, int lda, int ldb, int NBN, int WM) {
  __shared__ __align__(16) unsigned short lA[128 * 32];
  __shared__ __align__(16) unsigned short lB[128 * 32];
  const int tid = threadIdx.x;
  const int w = tid >> 6, lane = tid & 63;
  const int lr = lane & 15, lq = lane >> 4;
  const int l = blockIdx.x;
  const int xcd = l & 7, r = l >> 3;
  const int bm = xcd * WM + (r % WM);
  const int rest = r / WM;
  const int bn = rest % NBN;
  const size_t koff = (size_t)(rest / NBN) * K;  // split-K offset (K = per-block K)
  const unsigned short* Ab = A + (size_t)bm * 128 * lda + koff;
  const unsigned short* Bb = Bw + (size_t)bn * 128 * ldb + koff;
  const int wm = (w & 1) << 6, wn = (w >> 1) << 6;
  f32x4 acc[4][4] = {};
  const int kiters = K >> 5;
  const int c0 = tid, c1 = 256 + tid;
  const int r0 = c0 >> 2, o0 = (c0 & 3) << 3;
  const int r1 = c1 >> 2, o1 = (c1 & 3) << 3;
  for (int kt = 0; kt < kiters; ++kt) {
    const int kb = kt << 5;
    __syncthreads();
    async16(Ab + (size_t)r0 * lda + kb + o0, lA + c0 * 8);
    async16(Bb + (size_t)r0 * ldb + kb + o0, lB + c0 * 8);
    async16(Ab + (size_t)r1 * lda + kb + o1, lA + c1 * 8);
    async16(Bb + (size_t)r1 * ldb + kb + o1, lB + c1 * 8);
    __syncthreads();
    bf16x8 af[4], bfr[4];
#pragma unroll
    for (int i = 0; i < 4; ++i) af[i] = *(const bf16x8*)(lA + (wm + i * 16 + lr) * 32 + lq * 8);
#pragma unroll
    for (int i = 0; i < 4; ++i) bfr[i] = *(const bf16x8*)(lB + (wn + i * 16 + lr) * 32 + lq * 8);
#pragma unroll
    for (int i = 0; i < 4; ++i)
#pragma unroll
      for (int j = 0; j < 4; ++j)
        acc[i][j] = __builtin_amdgcn_mfma_f32_16x16x32_bf16(af[i], bfr[j], acc[i][j], 0, 0, 0);
  }
  const int which = (bn * 128) >> 10;  // EPI5: 0=Q,1=K,2=V (block-uniform; 1024%128==0)
#pragma unroll
  for (int i = 0; i < 4; ++i) {
#pragma unroll
    for (int j = 0; j < 4; ++j) {
      const int colg = bn * 128 + wn + j * 16 + lr;
      const float bi = (EPI == 6) ? 0.f : bias[colg];
      const int rowg0 = bm * 128 + wm + i * 16 + lq * 4;
#pragma unroll
      for (int r2 = 0; r2 < 4; ++r2) {
        const int rowg = rowg0 + r2;
        const float val = acc[i][j][r2] + bi;
        if (EPI == 5) {
          const int t = rowg >> 4, bb = rowg & 15;
          const int hh = (colg >> 6) & 15, dd = colg & 63;
          const size_t nn = (size_t)(bb * 16 + hh);
          unsigned short* q16 = (unsigned short*)Cout;
          if (which == 0) {
            if (rowg >= 1024) q16[(nn * 384 + (t - 64)) * 64 + dd] = f2bf(val);
          } else if (which == 1) {
            q16[KOFF + (nn * 448 + t) * 64 + dd] = f2bf(val);
          } else {
            q16[VOFF + (nn * 448 + t) * 64 + dd] = f2bf(val);
          }
        } else {
          const size_t idx = (size_t)rowg * N + colg;
          if (EPI == 2) ((float*)Cout)[idx] = val + resid[idx];
          else if (EPI == 3) ((unsigned short*)Cout)[idx] = f2bf(fmaxf(val, 0.f));
          else if (EPI == 6) atomicAdd(&((float*)Cout)[idx], acc[i][j][r2]);
        }
      }
    }
  }
}

// ---------------- V transpose: vb[n][t][d] -> vt[n][d][t] ----------------
__global__ __launch_bounds__(256) void vtrans(const unsigned short* __restrict__ vb,
                                              unsigned short* __restrict__ vt) {
  __shared__ __align__(16) unsigned short ls[64][80];
  const int kc = blockIdx.x, n = blockIdx.y;
  const int tid = threadIdx.x;
#pragma unroll
  for (int i = 0; i < 2; ++i) {
    const int c = i * 256 + tid;
    const int kk = c >> 3, dc = (c & 7) << 3;
    u16x8 val = *(const u16x8*)(vb + ((size_t)n * 448 + kc * 64 + kk) * 64 + dc);
    *(u16x8*)&ls[kk][dc] = val;
  }
  __syncthreads();
#pragma unroll
  for (int i = 0; i < 2; ++i) {
    const int c = i * 256 + tid;
    const int d = c >> 3, kx = (c & 7) << 3;
    u16x8 o;
#pragma unroll
    for (int j = 0; j < 8; ++j) o[j] = ls[kx + j][d];
    *(u16x8*)(vt + ((size_t)n * 64 + d) * 448 + kc * 64 + kx) = o;
  }
}

// ---------------- fused attention, S^T formulation, 4 waves/block ----------------
#define PST 468  // P row stride (u16): dword stride 234 == 10 mod 32 -> ~2-way (free)
__global__ __launch_bounds__(256) void attn_kernel(
    const unsigned short* __restrict__ qt_, const unsigned short* __restrict__ kt_,
    const unsigned short* __restrict__ vt_, unsigned short* __restrict__ attn) {
  __shared__ __align__(16) unsigned short P[16 * PST];  // 14976 B
  __shared__ float Rm[4][16], Rs[4][16], Rc[4][16], Rv[4][16], R2[4][16];
  __shared__ __align__(16) float OT[4][16][17];         // per-wave transpose buffers
  const int id = blockIdx.x;
  const int xcd = id & 7, j0 = id >> 3;
  const int n = xcd * 32 + (j0 & 31), qt = j0 >> 5;  // qt 0..23
  const int b = n >> 4, h = n & 15;
  const int tid = threadIdx.x, w = tid >> 6, lane = tid & 63;
  const int lr = lane & 15, lq = lane >> 4;

  const unsigned short* qp = qt_ + ((size_t)n * 384 + qt * 16 + lr) * 64 + lq * 8;
  const bf16x8 q0 = *(const bf16x8*)qp;
  const bf16x8 q1 = *(const bf16x8*)(qp + 32);

  // phase 1: S^T for 7 k-tiles. acc[t][r] = S[q=lr][k = (w*7+t)*16 + 4*lq + r]
  f32x4 acc[7];
#pragma unroll
  for (int t = 0; t < 7; ++t) {
    const unsigned short* kp = kt_ + ((size_t)n * 448 + (w * 7 + t) * 16 + lr) * 64 + lq * 8;
    const bf16x8 k0 = *(const bf16x8*)kp;
    const bf16x8 k1 = *(const bf16x8*)(kp + 32);
    f32x4 a = {0.f, 0.f, 0.f, 0.f};
    a = __builtin_amdgcn_mfma_f32_16x16x32_bf16(k0, q0, a, 0, 0, 0);
    a = __builtin_amdgcn_mfma_f32_16x16x32_bf16(k1, q1, a, 0, 0, 0);
    acc[t] = a;
  }

  // ---- pass 1: row max ----
  f32x4 m4 = acc[0];
#pragma unroll
  for (int t = 1; t < 7; ++t) {
    m4[0] = fmaxf(m4[0], acc[t][0]); m4[1] = fmaxf(m4[1], acc[t][1]);
    m4[2] = fmaxf(m4[2], acc[t][2]); m4[3] = fmaxf(m4[3], acc[t][3]);
  }
  float m = fmaxf(fmaxf(m4[0], m4[1]), fmaxf(m4[2], m4[3]));
  m = fmaxf(m, __shfl_xor(m, 16));
  m = fmaxf(m, __shfl_xor(m, 32));
  if (lq == 0) Rm[w][lr] = m;
  __syncthreads();
  m = fmaxf(fmaxf(Rm[0][lr], Rm[1][lr]), fmaxf(Rm[2][lr], Rm[3][lr]));

  // ---- exp in place; pass 2: sum + nonzero count ----
  f32x4 s4 = {0.f, 0.f, 0.f, 0.f}, c4 = {0.f, 0.f, 0.f, 0.f};
#pragma unroll
  for (int t = 0; t < 7; ++t) {
#pragma unroll
    for (int r = 0; r < 4; ++r) {
      const float e = __expf(acc[t][r] - m);
      acc[t][r] = e;
      s4[r] += e;
      if (e > 0.f) c4[r] += 1.f;
    }
  }
  float s = (s4[0] + s4[1]) + (s4[2] + s4[3]);
  float cnt = (c4[0] + c4[1]) + (c4[2] + c4[3]);
  s += __shfl_xor(s, 16); s += __shfl_xor(s, 32);
  cnt += __shfl_xor(cnt, 16); cnt += __shfl_xor(cnt, 32);
  if (lq == 0) { Rs[w][lr] = s; Rc[w][lr] = cnt; }
  __syncthreads();
  s = (Rs[0][lr] + Rs[1][lr]) + (Rs[2][lr] + Rs[3][lr]);
  cnt = (Rc[0][lr] + Rc[1][lr]) + (Rc[2][lr] + Rc[3][lr]);
  const float inv = 1.f / s;
  const float mean = 1.f / cnt;  // sum(p) == 1

  // ---- pass 3: variance of p over nonzeros ----
  f32x4 d4 = {0.f, 0.f, 0.f, 0.f};
#pragma unroll
  for (int t = 0; t < 7; ++t) {
#pragma unroll
    for (int r = 0; r < 4; ++r) {
      const float p = acc[t][r] * inv;
      const float dd = p - mean;
      if (acc[t][r] > 0.f) d4[r] += dd * dd;
    }
  }
  float dv = (d4[0] + d4[1]) + (d4[2] + d4[3]);
  dv += __shfl_xor(dv, 16); dv += __shfl_xor(dv, 32);
  if (lq == 0) Rv[w][lr] = dv;
  __syncthreads();
  dv = (Rv[0][lr] + Rv[1][lr]) + (Rv[2][lr] + Rv[3][lr]);
  const float thr = mean - 0.5f * sqrtf(dv / (cnt - 1.f));

  // ---- pass 4: survivor renormalizer (row max always survives: p_max >= mean >= thr) ----
  f32x4 t4 = {0.f, 0.f, 0.f, 0.f};
#pragma unroll
  for (int t = 0; t < 7; ++t) {
#pragma unroll
    for (int r = 0; r < 4; ++r) {
      if (!(acc[t][r] * inv < thr)) t4[r] += acc[t][r];
    }
  }
  float s2 = (t4[0] + t4[1]) + (t4[2] + t4[3]);
  s2 += __shfl_xor(s2, 16); s2 += __shfl_xor(s2, 32);
  if (lq == 0) R2[w][lr] = s2;
  __syncthreads();
  s2 = (R2[0][lr] + R2[1][lr]) + (R2[2][lr] + R2[3][lr]);
  const float inv2 = 1.f / s2;

  // ---- write P[q=lr][k] bf16 (wave w covers k in [w*112, w*112+112)) ----
#pragma unroll
  for (int t = 0; t < 7; ++t) {
#pragma unroll
    for (int rp = 0; rp < 4; rp += 2) {
      const float v0 = (acc[t][rp] * inv < thr) ? 0.f : acc[t][rp] * inv2;
      const float v1 = (acc[t][rp + 1] * inv < thr) ? 0.f : acc[t][rp + 1] * inv2;
      const unsigned int u = (unsigned int)f2bf(v0) | ((unsigned int)f2bf(v1) << 16);
      *(unsigned int*)&P[lr * PST + (w * 7 + t) * 16 + lq * 4 + rp] = u;
    }
  }
  __syncthreads();

  // phase 3: out^T[d][q] = V^T(64x448) . P(448x16). Wave w owns d-tile [w*16, w*16+16).
  f32x4 o = {0.f, 0.f, 0.f, 0.f};
#pragma unroll
  for (int c = 0; c < 14; ++c) {
    union { ushort4 hh[2]; bf16x8 v; } bf;
    bf.hh[0] = *(const ushort4*)&P[lr * PST + c * 32 + lq * 8];
    bf.hh[1] = *(const ushort4*)&P[lr * PST + c * 32 + lq * 8 + 4];
    const bf16x8 a = *(const bf16x8*)(vt_ + ((size_t)n * 64 + w * 16 + lr) * 448 + c * 32 + lq * 8);
    o = __builtin_amdgcn_mfma_f32_16x16x32_bf16(a, bf.v, o, 0, 0, 0);
  }

  // transpose 16x16 tile via wave-private LDS (no barrier: same-wave write->read)
#pragma unroll
  for (int r = 0; r < 4; ++r) OT[w][lq * 4 + r][lr] = o[r];
  const int qrow = lane >> 2, dg = lane & 3;
  ushort4 ov;
  ov.x = f2bf(OT[w][dg * 4 + 0][qrow]);
  ov.y = f2bf(OT[w][dg * 4 + 1][qrow]);
  ov.z = f2bf(OT[w][dg * 4 + 2][qrow]);
  ov.w = f2bf(OT[w][dg * 4 + 3][qrow]);
  *(ushort4*)(attn + ((size_t)(qt * 16 + qrow) * 16 + b) * 1024 + h * 64 + w * 16 + dg * 4) = ov;
}

// ---------------- launch ----------------
extern "C" void kernel_launch(void* const* d_in, const int* in_sizes, int n_in,
                              void* d_out, int out_size, void* d_ws, size_t ws_size,
                              hipStream_t stream) {
  (void)in_sizes; (void)n_in; (void)out_size; (void)ws_size;
  const float* x    = (const float*)d_in[0];
  const float* mem  = (const float*)d_in[1];
  const float* q_w  = (const float*)d_in[2];
  const float* q_b  = (const float*)d_in[3];
  const float* k_w  = (const float*)d_in[4];
  const float* k_b  = (const float*)d_in[5];
  const float* v_w  = (const float*)d_in[6];
  const float* v_b  = (const float*)d_in[7];
  const float* o_w  = (const float*)d_in[8];
  const float* o_b  = (const float*)d_in[9];
  const float* ln1w = (const float*)d_in[10];
  const float* ln1b = (const float*)d_in[11];
  const float* f1w  = (const float*)d_in[12];
  const float* f1b  = (const float*)d_in[13];
  const float* f2w  = (const float*)d_in[14];
  const float* f2b  = (const float*)d_in[15];
  const float* ln2w = (const float*)d_in[16];
  const float* ln2b = (const float*)d_in[17];

  unsigned short* WQ   = (unsigned short*)d_ws;        // 3x 1048576 contiguous = fused B
  unsigned short* WK   = WQ + 1048576;
  unsigned short* WV   = WK + 1048576;
  unsigned short* WO   = WV + 1048576;
  unsigned short* WF1  = WO + 1048576;                 // 4194304
  unsigned short* WF2  = WF1 + 4194304;                // 4194304
  unsigned short* ABUF = WF2 + 4194304;                // 7340032 (mem rows 0..1023, xn rows 1024..7167)
  unsigned short* QB   = ABUF + 7340032;               // 6291456 [n][384][64]; KB/VB at KOFF/VOFF
  unsigned short* KB   = QB + 6291456;                 // 7340032 [n][448][64]
  unsigned short* VB   = KB + 7340032;                 // 7340032 [n][448][64]
  unsigned short* VT   = VB + 7340032;                 // 7340032 [n][64][448]
  unsigned short* ATTN = VT + 7340032;                 // 6291456
  float*          X2   = (float*)(ATTN + 6291456);     // 6291456 f32
  float*          QKVB = (float*)ATTN;                 // 3072 f32, dead before attn writes ATTN
  unsigned short* XN2  = ATTN;                         // alias (attn dead after out-proj)
  unsigned short* HB   = ABUF;                         // alias (A/q/k/v staging dead after attention)

  // all weight/memory converts + bias concat in ONE launch
  cvt_all<<<13324, 256, 0, stream>>>(q_w, k_w, v_w, o_w, f1w, f2w, mem, q_b, k_b, v_b,
                                     WQ, WK, WV, WO, WF1, WF2, ABUF, QKVB);

  // LN1 -> xn (rows 1024.. of ABUF)
  ln_bf16<0><<<6144, 256, 0, stream>>>(x, ABUF + 1048576, ln1w, ln1b, nullptr, nullptr);

  // fused QKV: [mem;xn] x [Wq;Wk;Wv]^T, head-major epilogue. NBM=56 -> WM=7, NBN=24.
  gemm_bt<5><<<1344, 256, 0, stream>>>(ABUF, WQ, QKVB, nullptr, QB, 7168, 3072, 1024, 1024, 1024, 24, 7);

  vtrans<<<dim3(7, 256), 256, 0, stream>>>(VB, VT);
  attn_kernel<<<6144, 256, 0, stream>>>(QB, KB, VT, ATTN);

  // out-proj + residual -> X2 (f32). NBM=48 -> WM=6, NBN=8.
  gemm_bt<2><<<384, 256, 0, stream>>>(ATTN, WO, o_b, x, X2, 6144, 1024, 1024, 1024, 1024, 8, 6);

  // LN2 -> xn2, and prefill d_out = X2 + fc2_bias (fc2 accumulates into it)
  ln_bf16<1><<<6144, 256, 0, stream>>>(X2, XN2, ln2w, ln2b, f2b, (float*)d_out);

  // FFN, both on gemm_bt (engine family closed; TLP via grid size is the lever).
  // fc1: grid 1536 = 8 XCD x (6 m x 32 n) = 6 blocks/CU co-resident (round-0 proven).
  gemm_bt<3><<<1536, 256, 0, stream>>>(XN2, WF1, f1b, nullptr, HB, 6144, 4096, 1024, 1024, 1024, 32, 6);
  // fc2: split-K 4 (was 2): grid 1536 = 8 XCD x (6 m x 8 n x 4 kz) -> 6 blocks/CU,
  //      per-block K=1024; atomicAdd f32 into ln2-prefilled d_out (4 kz writers/tile,
  //      all on one XCD -> atomics stay in one L2).
  gemm_bt<6><<<1536, 256, 0, stream>>>(HB, WF2, nullptr, nullptr, d_out, 6144, 1024, 1024, 4096, 4096, 8, 6);
}

// Round 9
// 497.277 us; speedup vs baseline: 1.1605x; 1.0633x over previous
//
#include <hip/hip_runtime.h>

// ---------------- types / helpers ----------------
typedef __bf16 bf16x8 __attribute__((ext_vector_type(8)));
typedef float f32x4 __attribute__((ext_vector_type(4)));
typedef unsigned short u16x8 __attribute__((ext_vector_type(8)));

__device__ __forceinline__ unsigned short f2bf(float f) {
  union { float f; unsigned int u; } v; v.f = f;
  unsigned int r = v.u + 0x7fffu + ((v.u >> 16) & 1u);  // RNE
  return (unsigned short)(r >> 16);
}

__device__ __forceinline__ void async16(const unsigned short* g, unsigned short* l) {
  __builtin_amdgcn_global_load_lds(
      (const __attribute__((address_space(1))) unsigned int*)g,
      (__attribute__((address_space(3))) unsigned int*)l, 16, 0, 0);
}

// ---------------- fused converts: all weights + memory + bias concat, ONE launch ------
__global__ void cvt_all(const float* __restrict__ q_w, const float* __restrict__ k_w,
                        const float* __restrict__ v_w, const float* __restrict__ o_w,
                        const float* __restrict__ f1w, const float* __restrict__ f2w,
                        const float* __restrict__ mem,
                        const float* __restrict__ q_b, const float* __restrict__ k_b,
                        const float* __restrict__ v_b,
                        unsigned short* __restrict__ WQ, unsigned short* __restrict__ WK,
                        unsigned short* __restrict__ WV, unsigned short* __restrict__ WO,
                        unsigned short* __restrict__ WF1, unsigned short* __restrict__ WF2,
                        unsigned short* __restrict__ MEMB, float* __restrict__ QKVB) {
  const int bid = blockIdx.x;
  const float* src; unsigned short* dst; float scale = 1.f; int base;
  if (bid < 1024)       { src = q_w; dst = WQ;  scale = 0.125f; base = 0; }
  else if (bid < 2048)  { src = k_w; dst = WK;  base = 1024; }
  else if (bid < 3072)  { src = v_w; dst = WV;  base = 2048; }
  else if (bid < 4096)  { src = o_w; dst = WO;  base = 3072; }
  else if (bid < 8192)  { src = f1w; dst = WF1; base = 4096; }
  else if (bid < 12288) { src = f2w; dst = WF2; base = 8192; }
  else if (bid < 13312) { src = mem; dst = MEMB; base = 12288; }
  else {  // bias concat (12 blocks, 3072 elems), q-bias pre-scaled
    const int i = (bid - 13312) * 256 + threadIdx.x;
    QKVB[i] = (i < 1024) ? q_b[i] * 0.125f : (i < 2048 ? k_b[i - 1024] : v_b[i - 2048]);
    return;
  }
  const int i = (bid - base) * 256 + threadIdx.x;
  float4 v = ((const float4*)src)[i];
  ushort4 o;
  o.x = f2bf(v.x * scale); o.y = f2bf(v.y * scale);
  o.z = f2bf(v.z * scale); o.w = f2bf(v.w * scale);
  ((ushort4*)dst)[i] = o;
}

// ---------------- LayerNorm (per 1024-row) -> bf16 ----------------
template <int PREFILL>
__global__ __launch_bounds__(256) void ln_bf16(
    const float* __restrict__ src, unsigned short* __restrict__ dst,
    const float* __restrict__ g, const float* __restrict__ be,
    const float* __restrict__ fbias, float* __restrict__ dout) {
  const int row = blockIdx.x, tid = threadIdx.x;
  const float4 v = ((const float4*)(src + (size_t)row * 1024))[tid];
  if (PREFILL) {
    const float4 fb = ((const float4*)fbias)[tid];
    float4 r;
    r.x = v.x + fb.x; r.y = v.y + fb.y; r.z = v.z + fb.z; r.w = v.w + fb.w;
    ((float4*)(dout + (size_t)row * 1024))[tid] = r;
  }
  float s = v.x + v.y + v.z + v.w;
  float qq = v.x * v.x + v.y * v.y + v.z * v.z + v.w * v.w;
#pragma unroll
  for (int off = 32; off; off >>= 1) { s += __shfl_xor(s, off); qq += __shfl_xor(qq, off); }
  __shared__ float ps[4], pq[4];
  const int w = tid >> 6, lane = tid & 63;
  if (lane == 0) { ps[w] = s; pq[w] = qq; }
  __syncthreads();
  if (tid == 0) { ps[0] = ps[0] + ps[1] + ps[2] + ps[3]; pq[0] = pq[0] + pq[1] + pq[2] + pq[3]; }
  __syncthreads();
  const float mu = ps[0] * (1.f / 1024.f);
  const float var = pq[0] * (1.f / 1024.f) - mu * mu;
  const float rs = rsqrtf(var + 1e-5f);
  const float4 gv = ((const float4*)g)[tid];
  const float4 bv = ((const float4*)be)[tid];
  ushort4 o;
  o.x = f2bf((v.x - mu) * rs * gv.x + bv.x);
  o.y = f2bf((v.y - mu) * rs * gv.y + bv.y);
  o.z = f2bf((v.z - mu) * rs * gv.z + bv.z);
  o.w = f2bf((v.w - mu) * rs * gv.w + bv.w);
  ((ushort4*)(dst + (size_t)row * 1024))[tid] = o;
}

// ---------------- GEMM: C[M,N] = A[M,K] @ B[N,K]^T (+ bias), m97-style ----------------
// SESSION LEDGER (rounds 1-8): three deep-pipeline engines (2-phase BK=64, +T2
// swizzle, depth-3 ring BK=32) all parity-or-worse vs this kernel — signature
// MfmaUtil ~14%, VALUBusy ~6%, Occ ~15% = latency-bound at 1 block/CU. This
// 256-thr/16KB/56-VGPR kernel keeps 3-6 blocks/CU and m114 implicit wave overlap
// does the pipelining. fc2 split-K: 2 = 96.5us (WRITE 49MB) beats 4 = 131us
// (WRITE 96MB — atomic traffic > TLP gain, round 8).
// (256,4): cap 128 regs — no spill ((256,8) forced VGPR=32 -> scratch catastrophe,
// round 2), insurance vs co-compile perturbation (rule #19).
#define KOFF 6291456ull
#define VOFF 13631488ull
template <int EPI>
__global__ __launch_bounds__(256, 4) void gemm_bt(
    const unsigned short* __restrict__ A, const unsigned short* __restrict__ Bw,
    const float* __restrict__ bias, const float* __restrict__ resid,
    void* __restrict__ Cout, int M, int N, int K, int lda, int ldb, int NBN, int WM) {
  __shared__ __align__(16) unsigned short lA[128 * 32];
  __shared__ __align__(16) unsigned short lB[128 * 32];
  const int tid = threadIdx.x;
  const int w = tid >> 6, lane = tid & 63;
  const int lr = lane & 15, lq = lane >> 4;
  const int l = blockIdx.x;
  const int xcd = l & 7, r = l >> 3;
  const int bm = xcd * WM + (r % WM);
  const int rest = r / WM;
  const int bn = rest % NBN;
  const size_t koff = (size_t)(rest / NBN) * K;  // split-K offset (K = per-block K)
  const unsigned short* Ab = A + (size_t)bm * 128 * lda + koff;
  const unsigned short* Bb = Bw + (size_t)bn * 128 * ldb + koff;
  const int wm = (w & 1) << 6, wn = (w >> 1) << 6;
  f32x4 acc[4][4] = {};
  const int kiters = K >> 5;
  const int c0 = tid, c1 = 256 + tid;
  const int r0 = c0 >> 2, o0 = (c0 & 3) << 3;
  const int r1 = c1 >> 2, o1 = (c1 & 3) << 3;
  for (int kt = 0; kt < kiters; ++kt) {
    const int kb = kt << 5;
    __syncthreads();
    async16(Ab + (size_t)r0 * lda + kb + o0, lA + c0 * 8);
    async16(Bb + (size_t)r0 * ldb + kb + o0, lB + c0 * 8);
    async16(Ab + (size_t)r1 * lda + kb + o1, lA + c1 * 8);
    async16(Bb + (size_t)r1 * ldb + kb + o1, lB + c1 * 8);
    __syncthreads();
    bf16x8 af[4], bfr[4];
#pragma unroll
    for (int i = 0; i < 4; ++i) af[i] = *(const bf16x8*)(lA + (wm + i * 16 + lr) * 32 + lq * 8);
#pragma unroll
    for (int i = 0; i < 4; ++i) bfr[i] = *(const bf16x8*)(lB + (wn + i * 16 + lr) * 32 + lq * 8);
#pragma unroll
    for (int i = 0; i < 4; ++i)
#pragma unroll
      for (int j = 0; j < 4; ++j)
        acc[i][j] = __builtin_amdgcn_mfma_f32_16x16x32_bf16(af[i], bfr[j], acc[i][j], 0, 0, 0);
  }
  const int which = (bn * 128) >> 10;  // EPI5: 0=Q,1=K,2=V (block-uniform; 1024%128==0)
#pragma unroll
  for (int i = 0; i < 4; ++i) {
#pragma unroll
    for (int j = 0; j < 4; ++j) {
      const int colg = bn * 128 + wn + j * 16 + lr;
      const float bi = (EPI == 6) ? 0.f : bias[colg];
      const int rowg0 = bm * 128 + wm + i * 16 + lq * 4;
#pragma unroll
      for (int r2 = 0; r2 < 4; ++r2) {
        const int rowg = rowg0 + r2;
        const float val = acc[i][j][r2] + bi;
        if (EPI == 5) {
          const int t = rowg >> 4, bb = rowg & 15;
          const int hh = (colg >> 6) & 15, dd = colg & 63;
          const size_t nn = (size_t)(bb * 16 + hh);
          unsigned short* q16 = (unsigned short*)Cout;
          if (which == 0) {
            if (rowg >= 1024) q16[(nn * 384 + (t - 64)) * 64 + dd] = f2bf(val);
          } else if (which == 1) {
            q16[KOFF + (nn * 448 + t) * 64 + dd] = f2bf(val);
          } else {
            q16[VOFF + (nn * 448 + t) * 64 + dd] = f2bf(val);
          }
        } else {
          const size_t idx = (size_t)rowg * N + colg;
          if (EPI == 2) ((float*)Cout)[idx] = val + resid[idx];
          else if (EPI == 3) ((unsigned short*)Cout)[idx] = f2bf(fmaxf(val, 0.f));
          else if (EPI == 6) atomicAdd(&((float*)Cout)[idx], acc[i][j][r2]);
        }
      }
    }
  }
}

// ---------------- V transpose: vb[n][t][d] -> vt[n][d][t] ----------------
__global__ __launch_bounds__(256) void vtrans(const unsigned short* __restrict__ vb,
                                              unsigned short* __restrict__ vt) {
  __shared__ __align__(16) unsigned short ls[64][80];
  const int kc = blockIdx.x, n = blockIdx.y;
  const int tid = threadIdx.x;
#pragma unroll
  for (int i = 0; i < 2; ++i) {
    const int c = i * 256 + tid;
    const int kk = c >> 3, dc = (c & 7) << 3;
    u16x8 val = *(const u16x8*)(vb + ((size_t)n * 448 + kc * 64 + kk) * 64 + dc);
    *(u16x8*)&ls[kk][dc] = val;
  }
  __syncthreads();
#pragma unroll
  for (int i = 0; i < 2; ++i) {
    const int c = i * 256 + tid;
    const int d = c >> 3, kx = (c & 7) << 3;
    u16x8 o;
#pragma unroll
    for (int j = 0; j < 8; ++j) o[j] = ls[kx + j][d];
    *(u16x8*)(vt + ((size_t)n * 64 + d) * 448 + kc * 64 + kx) = o;
  }
}

// ---------------- fused attention, S^T formulation, 4 waves/block ----------------
#define PST 468  // P row stride (u16): dword stride 234 == 10 mod 32 -> ~2-way (free)
__global__ __launch_bounds__(256) void attn_kernel(
    const unsigned short* __restrict__ qt_, const unsigned short* __restrict__ kt_,
    const unsigned short* __restrict__ vt_, unsigned short* __restrict__ attn) {
  __shared__ __align__(16) unsigned short P[16 * PST];  // 14976 B
  __shared__ float Rm[4][16], Rs[4][16], Rc[4][16], Rv[4][16], R2[4][16];
  __shared__ __align__(16) float OT[4][16][17];         // per-wave transpose buffers
  const int id = blockIdx.x;
  const int xcd = id & 7, j0 = id >> 3;
  const int n = xcd * 32 + (j0 & 31), qt = j0 >> 5;  // qt 0..23
  const int b = n >> 4, h = n & 15;
  const int tid = threadIdx.x, w = tid >> 6, lane = tid & 63;
  const int lr = lane & 15, lq = lane >> 4;

  const unsigned short* qp = qt_ + ((size_t)n * 384 + qt * 16 + lr) * 64 + lq * 8;
  const bf16x8 q0 = *(const bf16x8*)qp;
  const bf16x8 q1 = *(const bf16x8*)(qp + 32);

  // phase 1: S^T for 7 k-tiles. acc[t][r] = S[q=lr][k = (w*7+t)*16 + 4*lq + r]
  f32x4 acc[7];
#pragma unroll
  for (int t = 0; t < 7; ++t) {
    const unsigned short* kp = kt_ + ((size_t)n * 448 + (w * 7 + t) * 16 + lr) * 64 + lq * 8;
    const bf16x8 k0 = *(const bf16x8*)kp;
    const bf16x8 k1 = *(const bf16x8*)(kp + 32);
    f32x4 a = {0.f, 0.f, 0.f, 0.f};
    a = __builtin_amdgcn_mfma_f32_16x16x32_bf16(k0, q0, a, 0, 0, 0);
    a = __builtin_amdgcn_mfma_f32_16x16x32_bf16(k1, q1, a, 0, 0, 0);
    acc[t] = a;
  }

  // ---- pass 1: row max ----
  f32x4 m4 = acc[0];
#pragma unroll
  for (int t = 1; t < 7; ++t) {
    m4[0] = fmaxf(m4[0], acc[t][0]); m4[1] = fmaxf(m4[1], acc[t][1]);
    m4[2] = fmaxf(m4[2], acc[t][2]); m4[3] = fmaxf(m4[3], acc[t][3]);
  }
  float m = fmaxf(fmaxf(m4[0], m4[1]), fmaxf(m4[2], m4[3]));
  m = fmaxf(m, __shfl_xor(m, 16));
  m = fmaxf(m, __shfl_xor(m, 32));
  if (lq == 0) Rm[w][lr] = m;
  __syncthreads();
  m = fmaxf(fmaxf(Rm[0][lr], Rm[1][lr]), fmaxf(Rm[2][lr], Rm[3][lr]));

  // ---- exp in place; pass 2: sum + nonzero count ----
  f32x4 s4 = {0.f, 0.f, 0.f, 0.f}, c4 = {0.f, 0.f, 0.f, 0.f};
#pragma unroll
  for (int t = 0; t < 7; ++t) {
#pragma unroll
    for (int r = 0; r < 4; ++r) {
      const float e = __expf(acc[t][r] - m);
      acc[t][r] = e;
      s4[r] += e;
      if (e > 0.f) c4[r] += 1.f;
    }
  }
  float s = (s4[0] + s4[1]) + (s4[2] + s4[3]);
  float cnt = (c4[0] + c4[1]) + (c4[2] + c4[3]);
  s += __shfl_xor(s, 16); s += __shfl_xor(s, 32);
  cnt += __shfl_xor(cnt, 16); cnt += __shfl_xor(cnt, 32);
  if (lq == 0) { Rs[w][lr] = s; Rc[w][lr] = cnt; }
  __syncthreads();
  s = (Rs[0][lr] + Rs[1][lr]) + (Rs[2][lr] + Rs[3][lr]);
  cnt = (Rc[0][lr] + Rc[1][lr]) + (Rc[2][lr] + Rc[3][lr]);
  const float inv = 1.f / s;
  const float mean = 1.f / cnt;  // sum(p) == 1

  // ---- pass 3: variance of p over nonzeros ----
  f32x4 d4 = {0.f, 0.f, 0.f, 0.f};
#pragma unroll
  for (int t = 0; t < 7; ++t) {
#pragma unroll
    for (int r = 0; r < 4; ++r) {
      const float p = acc[t][r] * inv;
      const float dd = p - mean;
      if (acc[t][r] > 0.f) d4[r] += dd * dd;
    }
  }
  float dv = (d4[0] + d4[1]) + (d4[2] + d4[3]);
  dv += __shfl_xor(dv, 16); dv += __shfl_xor(dv, 32);
  if (lq == 0) Rv[w][lr] = dv;
  __syncthreads();
  dv = (Rv[0][lr] + Rv[1][lr]) + (Rv[2][lr] + Rv[3][lr]);
  const float thr = mean - 0.5f * sqrtf(dv / (cnt - 1.f));

  // ---- pass 4: survivor renormalizer (row max always survives: p_max >= mean >= thr) ----
  f32x4 t4 = {0.f, 0.f, 0.f, 0.f};
#pragma unroll
  for (int t = 0; t < 7; ++t) {
#pragma unroll
    for (int r = 0; r < 4; ++r) {
      if (!(acc[t][r] * inv < thr)) t4[r] += acc[t][r];
    }
  }
  float s2 = (t4[0] + t4[1]) + (t4[2] + t4[3]);
  s2 += __shfl_xor(s2, 16); s2 += __shfl_xor(s2, 32);
  if (lq == 0) R2[w][lr] = s2;
  __syncthreads();
  s2 = (R2[0][lr] + R2[1][lr]) + (R2[2][lr] + R2[3][lr]);
  const float inv2 = 1.f / s2;

  // ---- write P[q=lr][k] bf16 (wave w covers k in [w*112, w*112+112)) ----
#pragma unroll
  for (int t = 0; t < 7; ++t) {
#pragma unroll
    for (int rp = 0; rp < 4; rp += 2) {
      const float v0 = (acc[t][rp] * inv < thr) ? 0.f : acc[t][rp] * inv2;
      const float v1 = (acc[t][rp + 1] * inv < thr) ? 0.f : acc[t][rp + 1] * inv2;
      const unsigned int u = (unsigned int)f2bf(v0) | ((unsigned int)f2bf(v1) << 16);
      *(unsigned int*)&P[lr * PST + (w * 7 + t) * 16 + lq * 4 + rp] = u;
    }
  }
  __syncthreads();

  // phase 3: out^T[d][q] = V^T(64x448) . P(448x16). Wave w owns d-tile [w*16, w*16+16).
  f32x4 o = {0.f, 0.f, 0.f, 0.f};
#pragma unroll
  for (int c = 0; c < 14; ++c) {
    union { ushort4 hh[2]; bf16x8 v; } bf;
    bf.hh[0] = *(const ushort4*)&P[lr * PST + c * 32 + lq * 8];
    bf.hh[1] = *(const ushort4*)&P[lr * PST + c * 32 + lq * 8 + 4];
    const bf16x8 a = *(const bf16x8*)(vt_ + ((size_t)n * 64 + w * 16 + lr) * 448 + c * 32 + lq * 8);
    o = __builtin_amdgcn_mfma_f32_16x16x32_bf16(a, bf.v, o, 0, 0, 0);
  }

  // transpose 16x16 tile via wave-private LDS (no barrier: same-wave write->read)
#pragma unroll
  for (int r = 0; r < 4; ++r) OT[w][lq * 4 + r][lr] = o[r];
  const int qrow = lane >> 2, dg = lane & 3;
  ushort4 ov;
  ov.x = f2bf(OT[w][dg * 4 + 0][qrow]);
  ov.y = f2bf(OT[w][dg * 4 + 1][qrow]);
  ov.z = f2bf(OT[w][dg * 4 + 2][qrow]);
  ov.w = f2bf(OT[w][dg * 4 + 3][qrow]);
  *(ushort4*)(attn + ((size_t)(qt * 16 + qrow) * 16 + b) * 1024 + h * 64 + w * 16 + dg * 4) = ov;
}

// ---------------- launch ----------------
extern "C" void kernel_launch(void* const* d_in, const int* in_sizes, int n_in,
                              void* d_out, int out_size, void* d_ws, size_t ws_size,
                              hipStream_t stream) {
  (void)in_sizes; (void)n_in; (void)out_size; (void)ws_size;
  const float* x    = (const float*)d_in[0];
  const float* mem  = (const float*)d_in[1];
  const float* q_w  = (const float*)d_in[2];
  const float* q_b  = (const float*)d_in[3];
  const float* k_w  = (const float*)d_in[4];
  const float* k_b  = (const float*)d_in[5];
  const float* v_w  = (const float*)d_in[6];
  const float* v_b  = (const float*)d_in[7];
  const float* o_w  = (const float*)d_in[8];
  const float* o_b  = (const float*)d_in[9];
  const float* ln1w = (const float*)d_in[10];
  const float* ln1b = (const float*)d_in[11];
  const float* f1w  = (const float*)d_in[12];
  const float* f1b  = (const float*)d_in[13];
  const float* f2w  = (const float*)d_in[14];
  const float* f2b  = (const float*)d_in[15];
  const float* ln2w = (const float*)d_in[16];
  const float* ln2b = (const float*)d_in[17];

  unsigned short* WQ   = (unsigned short*)d_ws;        // 3x 1048576 contiguous = fused B
  unsigned short* WK   = WQ + 1048576;
  unsigned short* WV   = WK + 1048576;
  unsigned short* WO   = WV + 1048576;
  unsigned short* WF1  = WO + 1048576;                 // 4194304
  unsigned short* WF2  = WF1 + 4194304;                // 4194304
  unsigned short* ABUF = WF2 + 4194304;                // 7340032 (mem rows 0..1023, xn rows 1024..7167)
  unsigned short* QB   = ABUF + 7340032;               // 6291456 [n][384][64]; KB/VB at KOFF/VOFF
  unsigned short* KB   = QB + 6291456;                 // 7340032 [n][448][64]
  unsigned short* VB   = KB + 7340032;                 // 7340032 [n][448][64]
  unsigned short* VT   = VB + 7340032;                 // 7340032 [n][64][448]
  unsigned short* ATTN = VT + 7340032;                 // 6291456
  float*          X2   = (float*)(ATTN + 6291456);     // 6291456 f32
  float*          QKVB = (float*)ATTN;                 // 3072 f32, dead before attn writes ATTN
  unsigned short* XN2  = ATTN;                         // alias (attn dead after out-proj)
  unsigned short* HB   = ABUF;                         // alias (A/q/k/v staging dead after attention)

  // all weight/memory converts + bias concat in ONE launch
  cvt_all<<<13324, 256, 0, stream>>>(q_w, k_w, v_w, o_w, f1w, f2w, mem, q_b, k_b, v_b,
                                     WQ, WK, WV, WO, WF1, WF2, ABUF, QKVB);

  // LN1 -> xn (rows 1024.. of ABUF)
  ln_bf16<0><<<6144, 256, 0, stream>>>(x, ABUF + 1048576, ln1w, ln1b, nullptr, nullptr);

  // fused QKV: [mem;xn] x [Wq;Wk;Wv]^T, head-major epilogue. NBM=56 -> WM=7, NBN=24.
  gemm_bt<5><<<1344, 256, 0, stream>>>(ABUF, WQ, QKVB, nullptr, QB, 7168, 3072, 1024, 1024, 1024, 24, 7);

  vtrans<<<dim3(7, 256), 256, 0, stream>>>(VB, VT);
  attn_kernel<<<6144, 256, 0, stream>>>(QB, KB, VT, ATTN);

  // out-proj + residual -> X2 (f32). NBM=48 -> WM=6, NBN=8.
  gemm_bt<2><<<384, 256, 0, stream>>>(ATTN, WO, o_b, x, X2, 6144, 1024, 1024, 1024, 1024, 8, 6);

  // LN2 -> xn2, and prefill d_out = X2 + fc2_bias (fc2 accumulates into it)
  ln_bf16<1><<<6144, 256, 0, stream>>>(X2, XN2, ln2w, ln2b, f2b, (float*)d_out);

  // FFN: best-of-measured configs combined (round 8 fc1 + round 3 fc2).
  // fc1: grid 1536 = 8 XCD x (6 m x 32 n) = 6 blocks/CU (round-8: ~23us faster
  //      than the gemm8 engine fc1).
  gemm_bt<3><<<1536, 256, 0, stream>>>(XN2, WF1, f1b, nullptr, HB, 6144, 4096, 1024, 1024, 1024, 32, 6);
  // fc2: split-K 2 (round-3 proven 96.5us; split-K 4 regressed to 131us via +55MB
  //      atomic traffic). grid 768 = 8 XCD x (6 m x 8 n x 2 kz), per-block K=2048;
  //      atomicAdd f32 into ln2-prefilled d_out.
  gemm_bt<6><<<768, 256, 0, stream>>>(HB, WF2, nullptr, nullptr, d_out, 6144, 1024, 2048, 4096, 4096, 8, 6);
}